// Round 1
// baseline (39.766 us; speedup 1.0000x reference)
//
#include <hip/hip_runtime.h>

// Flux_Kernels: 5-point stencil with Dirichlet BCs on all 4 sides.
// out[i,j] = D * ( s0*(nUp + nDown + nLeft + nRight) + 4*s1*u[i,j] )
// where off-grid neighbors are dirichlet_val[{0,1,2,3}] for {i=0, i=NX-1, j=0, j=NY-1}.
// u_coupled / t unused (is_retardation_a_func=False -> ret_inv = 1).

#define NX 4096
#define NY 4096
#define QUADS_PER_ROW (NY / 4)   // 1024

__global__ __launch_bounds__(256) void flux_stencil_kernel(
    const float* __restrict__ u,
    const float* __restrict__ D_eff,
    const float* __restrict__ dv,
    const float* __restrict__ st,
    float* __restrict__ out)
{
    const float D  = D_eff[0];
    const float s0 = st[0];
    const float s1 = st[1];

    const int tid = blockIdx.x * blockDim.x + threadIdx.x;   // one float4 per thread
    const int i = tid >> 10;           // row
    const int q = tid & (QUADS_PER_ROW - 1);
    const int j = q << 2;              // starting column of this quad

    const float4 c = *reinterpret_cast<const float4*>(u + (size_t)i * NY + j);

    float4 up, dn;
    if (i > 0) {
        up = *reinterpret_cast<const float4*>(u + (size_t)(i - 1) * NY + j);
    } else {
        const float d0 = dv[0];
        up = make_float4(d0, d0, d0, d0);
    }
    if (i < NX - 1) {
        dn = *reinterpret_cast<const float4*>(u + (size_t)(i + 1) * NY + j);
    } else {
        const float d1 = dv[1];
        dn = make_float4(d1, d1, d1, d1);
    }

    const float lft = (j == 0)      ? dv[2] : u[(size_t)i * NY + j - 1];
    const float rgt = (j + 4 == NY) ? dv[3] : u[(size_t)i * NY + j + 4];

    const float k1 = D * s0;        // coefficient on the 4 neighbors
    const float k4 = 4.0f * D * s1; // coefficient on the center

    float4 o;
    o.x = k1 * (up.x + dn.x + lft + c.y) + k4 * c.x;
    o.y = k1 * (up.y + dn.y + c.x + c.z) + k4 * c.y;
    o.z = k1 * (up.z + dn.z + c.y + c.w) + k4 * c.z;
    o.w = k1 * (up.w + dn.w + c.z + rgt) + k4 * c.w;

    *reinterpret_cast<float4*>(out + (size_t)i * NY + j) = o;
}

extern "C" void kernel_launch(void* const* d_in, const int* in_sizes, int n_in,
                              void* d_out, int out_size, void* d_ws, size_t ws_size,
                              hipStream_t stream) {
    const float* u_main    = (const float*)d_in[0];
    // d_in[1] = u_coupled (unused)
    const float* D_eff     = (const float*)d_in[2];
    const float* dirichlet = (const float*)d_in[3];
    const float* stencil   = (const float*)d_in[4];
    // d_in[5] = t (unused)
    float* out = (float*)d_out;

    const int total_quads = NX * NY / 4;           // 4,194,304
    const int block = 256;
    const int grid = total_quads / block;          // 16384

    flux_stencil_kernel<<<grid, block, 0, stream>>>(u_main, D_eff, dirichlet, stencil, out);
}

// Round 2
// 30.614 us; speedup vs baseline: 1.2989x; 1.2989x over previous
//
#include <hip/hip_runtime.h>

// Flux_Kernels: 5-point stencil with Dirichlet BCs on all 4 sides.
// out[i,j] = D * ( s0*(nUp + nDown + nLeft + nRight) + 4*s1*u[i,j] )
// Off-grid neighbors -> dirichlet_val[{0,1,2,3}] for {i=0, i=NX-1, j=0, j=NY-1}.
//
// Round-2 structure: one thread owns a 4-row x 4-col strip. Marches down the
// rows reusing up/center rows in registers (1 coalesced load + 1 store per
// output row). Horizontal halo comes from neighbor lanes via __shfl; only
// lanes 0/63 of each wave do a (single-line, L1-hit) edge load.

#define NX 4096
#define NY 4096
#define QPR 1024          // quads (float4s) per row
#define ROWS 4            // rows marched per thread

__global__ __launch_bounds__(256) void flux_stencil_kernel(
    const float* __restrict__ u,
    const float* __restrict__ D_eff,
    const float* __restrict__ dv,
    const float* __restrict__ st,
    float* __restrict__ out)
{
    const float D  = D_eff[0];
    const float s0 = st[0];
    const float s1 = st[1];
    const float k1 = D * s0;         // neighbor coefficient
    const float k4 = 4.0f * D * s1;  // center coefficient
    const float dvUp = dv[0], dvDn = dv[1], dvL = dv[2], dvR = dv[3];

    const int tid  = blockIdx.x * blockDim.x + threadIdx.x;
    const int band = tid >> 10;            // which 4-row band
    const int q    = tid & (QPR - 1);      // quad within row
    const int j    = q << 2;               // starting column
    const int i0   = band * ROWS;          // first row of this thread's strip
    const int lane = threadIdx.x & 63;

    const float* rowp = u + (size_t)i0 * NY + j;
    float*       outp = out + (size_t)i0 * NY + j;

    float4 up, cc;
    if (i0 == 0) up = make_float4(dvUp, dvUp, dvUp, dvUp);
    else         up = *reinterpret_cast<const float4*>(rowp - NY);
    cc = *reinterpret_cast<const float4*>(rowp);

    #pragma unroll
    for (int r = 0; r < ROWS; ++r) {
        const int i = i0 + r;

        float4 dn;
        if (i == NX - 1) dn = make_float4(dvDn, dvDn, dvDn, dvDn);
        else             dn = *reinterpret_cast<const float4*>(rowp + NY);

        // horizontal halo from neighbor lanes (same row, adjacent quads)
        float lft = __shfl_up(cc.w, 1);
        float rgt = __shfl_down(cc.x, 1);
        if (lane == 0)  lft = (j == 0)      ? dvL : rowp[-1];
        if (lane == 63) rgt = (j + 4 == NY) ? dvR : rowp[4];

        float4 o;
        o.x = k1 * (up.x + dn.x + lft  + cc.y) + k4 * cc.x;
        o.y = k1 * (up.y + dn.y + cc.x + cc.z) + k4 * cc.y;
        o.z = k1 * (up.z + dn.z + cc.y + cc.w) + k4 * cc.z;
        o.w = k1 * (up.w + dn.w + cc.z + rgt ) + k4 * cc.w;
        *reinterpret_cast<float4*>(outp) = o;

        up = cc;
        cc = dn;
        rowp += NY;
        outp += NY;
    }
}

extern "C" void kernel_launch(void* const* d_in, const int* in_sizes, int n_in,
                              void* d_out, int out_size, void* d_ws, size_t ws_size,
                              hipStream_t stream) {
    const float* u_main    = (const float*)d_in[0];
    // d_in[1] = u_coupled (unused)
    const float* D_eff     = (const float*)d_in[2];
    const float* dirichlet = (const float*)d_in[3];
    const float* stencil   = (const float*)d_in[4];
    // d_in[5] = t (unused)
    float* outp = (float*)d_out;

    const int total_threads = (NX / ROWS) * QPR;   // 1,048,576
    const int block = 256;
    const int grid = total_threads / block;        // 4096

    flux_stencil_kernel<<<grid, block, 0, stream>>>(u_main, D_eff, dirichlet, stencil, outp);
}

// Round 3
// 29.750 us; speedup vs baseline: 1.3367x; 1.0290x over previous
//
#include <hip/hip_runtime.h>

// Flux_Kernels: 5-point stencil with Dirichlet BCs on all 4 sides.
// out[i,j] = D * ( s0*(nUp + nDown + nLeft + nRight) + 4*s1*u[i,j] )
// Off-grid neighbors -> dirichlet_val[{0,1,2,3}] for {i=0, i=NX-1, j=0, j=NY-1}.
//
// Round-3 structure: one thread owns a 4-row x 4-col strip. ALL row loads
// (up + 4 center rows + down = 6 float4) are issued back-to-back into named
// registers before any compute, so each wave keeps ~6 KiB of HBM traffic in
// flight (round 2's VGPR=20 showed the compiler had serialized the loads).
// Horizontal halo via __shfl from neighbor lanes; lanes 0/63 patch with
// prefetched edge scalars.

#define NX 4096
#define NY 4096
#define QPR 1024          // quads (float4s) per row
#define ROWS 4            // rows per thread

__global__ __launch_bounds__(256) void flux_stencil_kernel(
    const float* __restrict__ u,
    const float* __restrict__ D_eff,
    const float* __restrict__ dv,
    const float* __restrict__ st,
    float* __restrict__ out)
{
    const float D  = D_eff[0];
    const float s0 = st[0];
    const float s1 = st[1];
    const float k1 = D * s0;         // neighbor coefficient
    const float k4 = 4.0f * D * s1;  // center coefficient
    const float dvUp = dv[0], dvDn = dv[1], dvL = dv[2], dvR = dv[3];

    const int tid  = blockIdx.x * blockDim.x + threadIdx.x;
    const int band = tid >> 10;            // which 4-row band
    const int q    = tid & (QPR - 1);      // quad within row
    const int j    = q << 2;               // starting column
    const int i0   = band * ROWS;          // first row of this thread's strip
    const int lane = threadIdx.x & 63;

    const float* rowp = u + (size_t)i0 * NY + j;
    float*       outp = out + (size_t)i0 * NY + j;

    // ---- issue ALL loads first (6 independent float4 + edge scalars) ----
    float4 rUp, r0, r1, r2, r3, rDn;
    r0 = *reinterpret_cast<const float4*>(rowp);
    r1 = *reinterpret_cast<const float4*>(rowp + NY);
    r2 = *reinterpret_cast<const float4*>(rowp + 2 * NY);
    r3 = *reinterpret_cast<const float4*>(rowp + 3 * NY);
    rUp = (i0 == 0)        ? make_float4(dvUp, dvUp, dvUp, dvUp)
                           : *reinterpret_cast<const float4*>(rowp - NY);
    rDn = (i0 + ROWS == NX) ? make_float4(dvDn, dvDn, dvDn, dvDn)
                           : *reinterpret_cast<const float4*>(rowp + 4 * NY);

    float lE0 = dvL, lE1 = dvL, lE2 = dvL, lE3 = dvL;
    float rE0 = dvR, rE1 = dvR, rE2 = dvR, rE3 = dvR;
    if (lane == 0 && j != 0) {
        lE0 = rowp[-1];
        lE1 = rowp[NY - 1];
        lE2 = rowp[2 * NY - 1];
        lE3 = rowp[3 * NY - 1];
    }
    if (lane == 63 && j + 4 != NY) {
        rE0 = rowp[4];
        rE1 = rowp[NY + 4];
        rE2 = rowp[2 * NY + 4];
        rE3 = rowp[3 * NY + 4];
    }

    // ---- compute + store ----
    #define ROW_OUT(UP, CC, DN, LE, RE, OFS)                                   \
    {                                                                          \
        float lft = __shfl_up(CC.w, 1);                                        \
        float rgt = __shfl_down(CC.x, 1);                                      \
        if (lane == 0)  lft = LE;                                              \
        if (lane == 63) rgt = RE;                                              \
        float4 o;                                                              \
        o.x = k1 * (UP.x + DN.x + lft  + CC.y) + k4 * CC.x;                    \
        o.y = k1 * (UP.y + DN.y + CC.x + CC.z) + k4 * CC.y;                    \
        o.z = k1 * (UP.z + DN.z + CC.y + CC.w) + k4 * CC.z;                    \
        o.w = k1 * (UP.w + DN.w + CC.z + rgt ) + k4 * CC.w;                    \
        *reinterpret_cast<float4*>(outp + (OFS)) = o;                          \
    }

    ROW_OUT(rUp, r0, r1, lE0, rE0, 0)
    ROW_OUT(r0,  r1, r2, lE1, rE1, NY)
    ROW_OUT(r1,  r2, r3, lE2, rE2, 2 * NY)
    ROW_OUT(r2,  r3, rDn, lE3, rE3, 3 * NY)

    #undef ROW_OUT
}

extern "C" void kernel_launch(void* const* d_in, const int* in_sizes, int n_in,
                              void* d_out, int out_size, void* d_ws, size_t ws_size,
                              hipStream_t stream) {
    const float* u_main    = (const float*)d_in[0];
    // d_in[1] = u_coupled (unused)
    const float* D_eff     = (const float*)d_in[2];
    const float* dirichlet = (const float*)d_in[3];
    const float* stencil   = (const float*)d_in[4];
    // d_in[5] = t (unused)
    float* outp = (float*)d_out;

    const int total_threads = (NX / ROWS) * QPR;   // 1,048,576
    const int block = 256;
    const int grid = total_threads / block;        // 4096

    flux_stencil_kernel<<<grid, block, 0, stream>>>(u_main, D_eff, dirichlet, stencil, outp);
}